// Round 10
// baseline (193.211 us; speedup 1.0000x reference)
//
#include <hip/hip_runtime.h>
#include <math.h>

#define NN 50000
#define EE 800000
#define INDIM 256
#define DD 32
#define HH 8
#define CC 256   // H*D
#define NEG 0.01f
#define NREP 8        // counter replicas == XCD count; rep = blockIdx%8 -> XCD-local atomics
#define SUBCAP 16     // slots per (node, replica): Poisson(2) tail safe
#define CAP 128       // NREP * SUBCAP

typedef __attribute__((ext_vector_type(8))) short bf16x8;
typedef __attribute__((ext_vector_type(4))) float f32x4;

__device__ __forceinline__ unsigned short f32_to_bf16_rne(float f) {
  unsigned u = __float_as_uint(f);
  u += 0x7fffu + ((u >> 16) & 1u);
  return (unsigned short)(u >> 16);
}
__device__ __forceinline__ float bf16_to_f32(unsigned short b) {
  return __uint_as_float((unsigned)b << 16);
}

// ---------- fused: dtype-detect + convert + XCD-local histogram + bucket scatter + W->bf16 ----------
// counts[rep][node]: replica rep is only touched by blocks with blockIdx%8==rep,
// which land on one XCD (round-robin dispatch) -> atomics stay L2-local, no
// cross-XCD line ping-pong. Edge e of dst d goes to csr16[d*128 + rep*16 + slot].
__global__ __launch_bounds__(256) void k_prep(const unsigned* __restrict__ sraw,
                                              const unsigned* __restrict__ draw,
                                              int* __restrict__ counts,
                                              unsigned short* __restrict__ csr16,
                                              const float* __restrict__ W,
                                              unsigned short* __restrict__ WbT) {
  __shared__ int sflag;
  if (threadIdx.x == 0) sflag = 0;
  __syncthreads();
  const int gt = blockIdx.x * 256 + threadIdx.x;
  unsigned v = 0;
#pragma unroll
  for (int i = 0; i < 4; ++i) {
    int e = (gt * 4 + i) % (EE / 2);
    v |= sraw[2 * e + 1] | draw[2 * e + 1];
  }
  if (v) atomicOr(&sflag, 1);
  __syncthreads();
  const int is32 = sflag;   // 1 => int32 indices

  const int rep = blockIdx.x & (NREP - 1);
  int* __restrict__ mycounts = counts + rep * NN;

  const int stride = gridDim.x * blockDim.x;
  for (int e = gt; e < EE; e += stride) {
    int sv, dv;
    if (is32) {
      sv = ((const int*)sraw)[e];
      dv = ((const int*)draw)[e];
    } else {
      sv = (int)((const long long*)sraw)[e];
      dv = (int)((const long long*)draw)[e];
    }
    int slot = atomicAdd(&mycounts[dv], 1);
    csr16[(dv << 7) + (rep << 4) + slot] = (unsigned short)sv;
  }

  // W -> WbT[n][k] = W[h][k][d], n=h*32+d (B^T layout)
  if (gt < INDIM * CC) {
    int n = gt >> 8, k = gt & 255;
    int hh = n >> 5, d = n & 31;
    WbT[gt] = f32_to_bf16_rne(W[(size_t)hh * 8192 + k * 32 + d]);
  }
}

// ---------- z = h @ W via bf16 MFMA (swapped operands); el/er fused ----------
__global__ __launch_bounds__(512) void k_gemm(const float* __restrict__ h,
                                              const unsigned short* __restrict__ WbT,
                                              const float* __restrict__ attn_w,
                                              unsigned short* __restrict__ z,
                                              float* __restrict__ el,
                                              float* __restrict__ er) {
  __shared__ short sA[64 * 256];   // 32 KB, [64 nodes][256 k], chunk-swizzled
  const int t = threadIdx.x;
  const int l = t & 63;
  const int w = t >> 6;            // wave index == head
  const int row0 = blockIdx.x * 64;

#pragma unroll
  for (int i = 0; i < 4; ++i) {
    int q = i * 512 + t;
    int row = q >> 5, c = q & 31;
    int grow = row0 + row; if (grow >= NN) grow = NN - 1;
    const float* src = &h[(size_t)grow * 256 + c * 8];
    float4 f0 = *reinterpret_cast<const float4*>(src);
    float4 f1 = *reinterpret_cast<const float4*>(src + 4);
    bf16x8 vv;
    vv[0] = (short)f32_to_bf16_rne(f0.x); vv[1] = (short)f32_to_bf16_rne(f0.y);
    vv[2] = (short)f32_to_bf16_rne(f0.z); vv[3] = (short)f32_to_bf16_rne(f0.w);
    vv[4] = (short)f32_to_bf16_rne(f1.x); vv[5] = (short)f32_to_bf16_rne(f1.y);
    vv[6] = (short)f32_to_bf16_rne(f1.z); vv[7] = (short)f32_to_bf16_rne(f1.w);
    int sc = c ^ (row & 7);
    *reinterpret_cast<bf16x8*>(&sA[row * 256 + sc * 8]) = vv;
  }

  bf16x8 bf[2][8];
  {
    const int n = w * 32 + (l & 15);
    const int kb = (l >> 4) * 8;
#pragma unroll
    for (int c = 0; c < 2; ++c)
#pragma unroll
      for (int kk = 0; kk < 8; ++kk)
        bf[c][kk] = *reinterpret_cast<const bf16x8*>(
            &WbT[(size_t)(n + c * 16) * 256 + kk * 32 + kb]);
  }

  f32x4 acc[4][2];
#pragma unroll
  for (int m = 0; m < 4; ++m)
#pragma unroll
    for (int c = 0; c < 2; ++c) acc[m][c] = (f32x4){0.f, 0.f, 0.f, 0.f};

  __syncthreads();

#pragma unroll
  for (int kk = 0; kk < 8; ++kk) {
    bf16x8 af[4];
#pragma unroll
    for (int m = 0; m < 4; ++m) {
      int row = m * 16 + (l & 15);
      int chunk = kk * 4 + (l >> 4);
      int sc = chunk ^ (row & 7);
      af[m] = *reinterpret_cast<const bf16x8*>(&sA[row * 256 + sc * 8]);
    }
#pragma unroll
    for (int m = 0; m < 4; ++m)
#pragma unroll
      for (int c = 0; c < 2; ++c)
        acc[m][c] = __builtin_amdgcn_mfma_f32_16x16x32_bf16(bf[c][kk], af[m], acc[m][c], 0, 0, 0);
  }

  // acc[m][c][r]: node = row0+m*16+(l&15), feat = w*32 + c*16 + (l>>4)*4 + r
#pragma unroll
  for (int m = 0; m < 4; ++m) {
    int node = row0 + m * 16 + (l & 15);
    if (node < NN) {
#pragma unroll
      for (int c = 0; c < 2; ++c) {
        ushort4 pk;
        pk.x = f32_to_bf16_rne(acc[m][c][0]);
        pk.y = f32_to_bf16_rne(acc[m][c][1]);
        pk.z = f32_to_bf16_rne(acc[m][c][2]);
        pk.w = f32_to_bf16_rne(acc[m][c][3]);
        *reinterpret_cast<ushort4*>(
            &z[(size_t)node * CC + w * 32 + c * 16 + ((l >> 4) << 2)]) = pk;
      }
    }
  }

  float alc[2][4], arc[2][4];
#pragma unroll
  for (int c = 0; c < 2; ++c)
#pragma unroll
    for (int r = 0; r < 4; ++r) {
      int d = c * 16 + ((l >> 4) << 2) + r;
      alc[c][r] = attn_w[w * 64 + d];
      arc[c][r] = attn_w[w * 64 + 32 + d];
    }
#pragma unroll
  for (int m = 0; m < 4; ++m) {
    float pl = 0.f, pr = 0.f;
#pragma unroll
    for (int c = 0; c < 2; ++c)
#pragma unroll
      for (int r = 0; r < 4; ++r) {
        pl += acc[m][c][r] * alc[c][r];
        pr += acc[m][c][r] * arc[c][r];
      }
    pl += __shfl_xor(pl, 16); pl += __shfl_xor(pl, 32);
    pr += __shfl_xor(pr, 16); pr += __shfl_xor(pr, 32);
    if ((l >> 4) == 0) {
      int node = row0 + m * 16 + l;
      if (node < NN) {
        el[(size_t)node * HH + w] = pl;
        er[(size_t)node * HH + w] = pr;
      }
    }
  }
}

// ---------- per-node softmax-aggregate (round-4 body; 8 sub-buckets per node) ----------
#define AGG_WAVES 8192
__global__ __launch_bounds__(256) void k_agg(const unsigned short* __restrict__ z,
                                             const float* __restrict__ el,
                                             const float* __restrict__ er,
                                             const int* __restrict__ counts,
                                             const unsigned short* __restrict__ csr16,
                                             float* __restrict__ out) {
  const int gw = blockIdx.x * 4 + (threadIdx.x >> 6);
  const int l = threadIdx.x & 63;
  const int head = l >> 3;

  for (int n = gw; n < NN; n += AGG_WAVES) {
    const float ern = er[(size_t)n * HH + head];
    const int base = n << 7;

    float den = 0.f;
    float a0 = 0.f, a1 = 0.f, a2 = 0.f, a3 = 0.f;
    int tot = 0;
#pragma unroll
    for (int rep = 0; rep < NREP; ++rep) {
      const int cnt = counts[rep * NN + n];   // wave-uniform broadcast load
      tot += cnt;
      const int sb = base + (rep << 4);
#pragma unroll 2
      for (int j = 0; j < cnt; ++j) {
        int s = (int)csr16[sb + j];
        float v = el[(size_t)s * HH + head] + ern;
        v = (v > 0.f) ? v : v * NEG;
        float wgt = __expf(v);
        ushort4 zv = *reinterpret_cast<const ushort4*>(&z[(size_t)s * CC + 4 * l]);
        den += wgt;
        a0 += wgt * bf16_to_f32(zv.x);
        a1 += wgt * bf16_to_f32(zv.y);
        a2 += wgt * bf16_to_f32(zv.z);
        a3 += wgt * bf16_to_f32(zv.w);
      }
    }
    const float rd = (tot > 0) ? (1.f / den) : 0.f;
    float4 o;
    o.x = a0 * rd; o.y = a1 * rd; o.z = a2 * rd; o.w = a3 * rd;
    *reinterpret_cast<float4*>(&out[(size_t)n * CC + 4 * l]) = o;
  }
}

extern "C" void kernel_launch(void* const* d_in, const int* in_sizes, int n_in,
                              void* d_out, int out_size, void* d_ws, size_t ws_size,
                              hipStream_t stream) {
  const float* h      = (const float*)d_in[0];
  const float* W      = (const float*)d_in[1];
  const float* attn_w = (const float*)d_in[2];
  const void*  src_raw = d_in[3];
  const void*  dst_raw = d_in[4];
  float* out = (float*)d_out;

  char* ws = (char*)d_ws;
  size_t off = 0;
  unsigned short* z   = (unsigned short*)(ws + off); off += (size_t)NN * CC * 2;     // 25.6 MB
  unsigned short* WbT = (unsigned short*)(ws + off); off += (size_t)INDIM * CC * 2;  // 128 KB
  float* el = (float*)(ws + off); off += (size_t)NN * HH * 4;   // 1.6 MB
  float* er = (float*)(ws + off); off += (size_t)NN * HH * 4;   // 1.6 MB
  int* counts = (int*)(ws + off); off += (size_t)NREP * NN * 4; // 1.6 MB (memset)
  unsigned short* csr16 = (unsigned short*)(ws + off); off += (size_t)NN * CAP * 2;  // 12.8 MB

  hipMemsetAsync(counts, 0, (size_t)NREP * NN * 4, stream);

  k_prep<<<1024, 256, 0, stream>>>((const unsigned*)src_raw, (const unsigned*)dst_raw,
                                   counts, csr16, W, WbT);

  k_gemm<<<(NN + 63) / 64, 512, 0, stream>>>(h, WbT, attn_w, z, el, er);

  k_agg<<<AGG_WAVES / 4, 256, 0, stream>>>(z, el, er, counts, csr16, out);
}

// Round 11
// 166.102 us; speedup vs baseline: 1.1632x; 1.1632x over previous
//
#include <hip/hip_runtime.h>
#include <math.h>

#define NN 50000
#define EE 800000
#define INDIM 256
#define DD 32
#define HH 8
#define CC 256   // H*D
#define NEG 0.01f
#define NREP 8        // counter replicas == XCD count (rep-major => XCD-local lines)
#define NSCAN 49      // ceil(NN/1024)
#define PREP_GRID 1024
#define PREP_STRIDE (PREP_GRID * 256)

typedef __attribute__((ext_vector_type(8))) short bf16x8;
typedef __attribute__((ext_vector_type(4))) float f32x4;

__device__ __forceinline__ unsigned short f32_to_bf16_rne(float f) {
  unsigned u = __float_as_uint(f);
  u += 0x7fffu + ((u >> 16) & 1u);
  return (unsigned short)(u >> 16);
}
__device__ __forceinline__ float bf16_to_f32(unsigned short b) {
  return __uint_as_float((unsigned)b << 16);
}

// ---------- prep: detect + convert(->ushort) + XCD-local histogram + W->bf16 ----------
// counts8[rep*NN + n]: rep = blockIdx%8. Blocks round-robin XCDs by blockIdx,
// and replicas are 200KB apart -> histogram atomics stay XCD-L2-local.
__global__ __launch_bounds__(256) void k_prep(const unsigned* __restrict__ sraw,
                                              const unsigned* __restrict__ draw,
                                              int* __restrict__ counts8,
                                              unsigned short* __restrict__ s16,
                                              unsigned short* __restrict__ d16,
                                              unsigned short* __restrict__ slot16,
                                              const float* __restrict__ W,
                                              unsigned short* __restrict__ WbT) {
  __shared__ int sflag;
  if (threadIdx.x == 0) sflag = 0;
  __syncthreads();
  const int gt = blockIdx.x * 256 + threadIdx.x;
  unsigned v = 0;
#pragma unroll
  for (int i = 0; i < 4; ++i) {
    int e = (gt * 4 + i) % (EE / 2);
    v |= sraw[2 * e + 1] | draw[2 * e + 1];
  }
  if (v) atomicOr(&sflag, 1);
  __syncthreads();
  const int is32 = sflag;   // 1 => int32 indices

  const int rep = blockIdx.x & (NREP - 1);
  int* __restrict__ mycounts = counts8 + rep * NN;

  for (int e = gt; e < EE; e += PREP_STRIDE) {
    int sv, dv;
    if (is32) {
      sv = ((const int*)sraw)[e];
      dv = ((const int*)draw)[e];
    } else {
      sv = (int)((const long long*)sraw)[e];
      dv = (int)((const long long*)draw)[e];
    }
    s16[e] = (unsigned short)sv;
    d16[e] = (unsigned short)dv;
    slot16[e] = (unsigned short)atomicAdd(&mycounts[dv], 1);
  }

  // W -> WbT[n][k] = W[h][k][d], n=h*32+d (B^T layout)
  if (gt < INDIM * CC) {
    int n = gt >> 8, k = gt & 255;
    int hh = n >> 5, d = n & 31;
    WbT[gt] = f32_to_bf16_rne(W[(size_t)hh * 8192 + k * 32 + d]);
  }
}

// ---------- z = h @ W via bf16 MFMA (swapped operands); el/er fused ----------
__global__ __launch_bounds__(512) void k_gemm(const float* __restrict__ h,
                                              const unsigned short* __restrict__ WbT,
                                              const float* __restrict__ attn_w,
                                              unsigned short* __restrict__ z,
                                              float* __restrict__ el,
                                              float* __restrict__ er) {
  __shared__ short sA[64 * 256];   // 32 KB, [64 nodes][256 k], chunk-swizzled
  const int t = threadIdx.x;
  const int l = t & 63;
  const int w = t >> 6;            // wave index == head
  const int row0 = blockIdx.x * 64;

#pragma unroll
  for (int i = 0; i < 4; ++i) {
    int q = i * 512 + t;
    int row = q >> 5, c = q & 31;
    int grow = row0 + row; if (grow >= NN) grow = NN - 1;
    const float* src = &h[(size_t)grow * 256 + c * 8];
    float4 f0 = *reinterpret_cast<const float4*>(src);
    float4 f1 = *reinterpret_cast<const float4*>(src + 4);
    bf16x8 vv;
    vv[0] = (short)f32_to_bf16_rne(f0.x); vv[1] = (short)f32_to_bf16_rne(f0.y);
    vv[2] = (short)f32_to_bf16_rne(f0.z); vv[3] = (short)f32_to_bf16_rne(f0.w);
    vv[4] = (short)f32_to_bf16_rne(f1.x); vv[5] = (short)f32_to_bf16_rne(f1.y);
    vv[6] = (short)f32_to_bf16_rne(f1.z); vv[7] = (short)f32_to_bf16_rne(f1.w);
    int sc = c ^ (row & 7);
    *reinterpret_cast<bf16x8*>(&sA[row * 256 + sc * 8]) = vv;
  }

  bf16x8 bf[2][8];
  {
    const int n = w * 32 + (l & 15);
    const int kb = (l >> 4) * 8;
#pragma unroll
    for (int c = 0; c < 2; ++c)
#pragma unroll
      for (int kk = 0; kk < 8; ++kk)
        bf[c][kk] = *reinterpret_cast<const bf16x8*>(
            &WbT[(size_t)(n + c * 16) * 256 + kk * 32 + kb]);
  }

  f32x4 acc[4][2];
#pragma unroll
  for (int m = 0; m < 4; ++m)
#pragma unroll
    for (int c = 0; c < 2; ++c) acc[m][c] = (f32x4){0.f, 0.f, 0.f, 0.f};

  __syncthreads();

#pragma unroll
  for (int kk = 0; kk < 8; ++kk) {
    bf16x8 af[4];
#pragma unroll
    for (int m = 0; m < 4; ++m) {
      int row = m * 16 + (l & 15);
      int chunk = kk * 4 + (l >> 4);
      int sc = chunk ^ (row & 7);
      af[m] = *reinterpret_cast<const bf16x8*>(&sA[row * 256 + sc * 8]);
    }
#pragma unroll
    for (int m = 0; m < 4; ++m)
#pragma unroll
      for (int c = 0; c < 2; ++c)
        acc[m][c] = __builtin_amdgcn_mfma_f32_16x16x32_bf16(bf[c][kk], af[m], acc[m][c], 0, 0, 0);
  }

  // acc[m][c][r]: node = row0+m*16+(l&15), feat = w*32 + c*16 + (l>>4)*4 + r
#pragma unroll
  for (int m = 0; m < 4; ++m) {
    int node = row0 + m * 16 + (l & 15);
    if (node < NN) {
#pragma unroll
      for (int c = 0; c < 2; ++c) {
        ushort4 pk;
        pk.x = f32_to_bf16_rne(acc[m][c][0]);
        pk.y = f32_to_bf16_rne(acc[m][c][1]);
        pk.z = f32_to_bf16_rne(acc[m][c][2]);
        pk.w = f32_to_bf16_rne(acc[m][c][3]);
        *reinterpret_cast<ushort4*>(
            &z[(size_t)node * CC + w * 32 + c * 16 + ((l >> 4) << 2)]) = pk;
      }
    }
  }

  float alc[2][4], arc[2][4];
#pragma unroll
  for (int c = 0; c < 2; ++c)
#pragma unroll
    for (int r = 0; r < 4; ++r) {
      int d = c * 16 + ((l >> 4) << 2) + r;
      alc[c][r] = attn_w[w * 64 + d];
      arc[c][r] = attn_w[w * 64 + 32 + d];
    }
#pragma unroll
  for (int m = 0; m < 4; ++m) {
    float pl = 0.f, pr = 0.f;
#pragma unroll
    for (int c = 0; c < 2; ++c)
#pragma unroll
      for (int r = 0; r < 4; ++r) {
        pl += acc[m][c][r] * alc[c][r];
        pr += acc[m][c][r] * arc[c][r];
      }
    pl += __shfl_xor(pl, 16); pl += __shfl_xor(pl, 32);
    pr += __shfl_xor(pr, 16); pr += __shfl_xor(pr, 32);
    if ((l >> 4) == 0) {
      int node = row0 + m * 16 + l;
      if (node < NN) {
        el[(size_t)node * HH + w] = pl;
        er[(size_t)node * HH + w] = pr;
      }
    }
  }
}

// ---------- scan: fold 8 rep-counts -> degree scan + per-(node,rep) offsets ----------
__global__ __launch_bounds__(1024) void k_scan(const int* __restrict__ counts8,
                                               int* __restrict__ row_start,
                                               int* __restrict__ partial,
                                               unsigned char* __restrict__ offs8) {
  __shared__ int s[1024];
  const int tid = threadIdx.x;
  const int i = blockIdx.x * 1024 + tid;
  int deg = 0;
  if (i < NN) {
    unsigned pack0 = 0, pack1 = 0;
    int run = 0;
#pragma unroll
    for (int r = 0; r < NREP; ++r) {
      int c = counts8[r * NN + i];
      if (r < 4) pack0 |= (unsigned)run << (8 * r);
      else       pack1 |= (unsigned)run << (8 * (r - 4));
      run += c;
    }
    deg = run;
    uint2 pk; pk.x = pack0; pk.y = pack1;
    *reinterpret_cast<uint2*>(&offs8[(size_t)i * 8]) = pk;
  }
  s[tid] = deg;
  __syncthreads();
  for (int off = 1; off < 1024; off <<= 1) {
    int tv = (tid >= off) ? s[tid - off] : 0;
    __syncthreads();
    s[tid] += tv;
    __syncthreads();
  }
  if (i < NN) row_start[i] = s[tid] - deg;         // exclusive within chunk
  if (tid == 1023) partial[blockIdx.x] = s[1023];  // raw chunk total
}

// helper: wave-0 computes exclusive prefix of NSCAN partials into sbase[]
__device__ __forceinline__ void block_base_scan(const int* __restrict__ partial,
                                                int* __restrict__ sbase) {
  if (threadIdx.x < 64) {
    int l = threadIdx.x;
    int x = (l < NSCAN) ? partial[l] : 0;
    int orig = x;
#pragma unroll
    for (int off = 1; off < 64; off <<= 1) {
      int y = __shfl_up(x, off);
      if (l >= off) x += y;
    }
    sbase[l] = x - orig;
  }
  __syncthreads();
}

// ---------- scatter: atomic-free, contiguous per-node CSR ----------
// rep recomputed from e (prep's static e->block map): rep = ((e % PREP_STRIDE) >> 8) & 7
__global__ __launch_bounds__(256) void k_scatter(const unsigned short* __restrict__ s16,
                                                 const unsigned short* __restrict__ d16,
                                                 const unsigned short* __restrict__ slot16,
                                                 const unsigned char* __restrict__ offs8,
                                                 const int* __restrict__ row_start,
                                                 const int* __restrict__ partial,
                                                 unsigned short* __restrict__ csr16) {
  __shared__ int sbase[64];
  block_base_scan(partial, sbase);
  int stride = gridDim.x * blockDim.x;
  for (int e = blockIdx.x * blockDim.x + threadIdx.x; e < EE; e += stride) {
    int dn = (int)d16[e];
    int rep = ((e & (PREP_STRIDE - 1)) >> 8) & (NREP - 1);
    int pos = row_start[dn] + sbase[dn >> 10] + (int)offs8[dn * 8 + rep] + (int)slot16[e];
    csr16[pos] = s16[e];
  }
}

// ---------- per-node softmax-aggregate (round-4/7 known-best body) ----------
#define AGG_WAVES 8192
__global__ __launch_bounds__(256) void k_agg(const unsigned short* __restrict__ z,
                                             const float* __restrict__ el,
                                             const float* __restrict__ er,
                                             const int* __restrict__ row_start,
                                             const int* __restrict__ partial,
                                             const unsigned short* __restrict__ csr16,
                                             float* __restrict__ out) {
  __shared__ int sbase[64];
  block_base_scan(partial, sbase);

  const int gw = blockIdx.x * 4 + (threadIdx.x >> 6);
  const int l = threadIdx.x & 63;
  const int head = l >> 3;

  for (int n = gw; n < NN; n += AGG_WAVES) {
    const int beg = row_start[n] + sbase[n >> 10];
    const int end = (n == NN - 1) ? EE : (row_start[n + 1] + sbase[(n + 1) >> 10]);
    const float ern = er[(size_t)n * HH + head];

    float den = 0.f;
    float a0 = 0.f, a1 = 0.f, a2 = 0.f, a3 = 0.f;
#pragma unroll 4
    for (int p = beg; p < end; ++p) {
      int s = (int)csr16[p];
      float v = el[(size_t)s * HH + head] + ern;
      v = (v > 0.f) ? v : v * NEG;
      float wgt = __expf(v);
      ushort4 zv = *reinterpret_cast<const ushort4*>(&z[(size_t)s * CC + 4 * l]);
      den += wgt;
      a0 += wgt * bf16_to_f32(zv.x);
      a1 += wgt * bf16_to_f32(zv.y);
      a2 += wgt * bf16_to_f32(zv.z);
      a3 += wgt * bf16_to_f32(zv.w);
    }
    const float rd = (end > beg) ? (1.f / den) : 0.f;
    float4 o;
    o.x = a0 * rd; o.y = a1 * rd; o.z = a2 * rd; o.w = a3 * rd;
    *reinterpret_cast<float4*>(&out[(size_t)n * CC + 4 * l]) = o;
  }
}

extern "C" void kernel_launch(void* const* d_in, const int* in_sizes, int n_in,
                              void* d_out, int out_size, void* d_ws, size_t ws_size,
                              hipStream_t stream) {
  const float* h      = (const float*)d_in[0];
  const float* W      = (const float*)d_in[1];
  const float* attn_w = (const float*)d_in[2];
  const void*  src_raw = d_in[3];
  const void*  dst_raw = d_in[4];
  float* out = (float*)d_out;

  char* ws = (char*)d_ws;
  size_t off = 0;
  unsigned short* z   = (unsigned short*)(ws + off); off += (size_t)NN * CC * 2;     // 25.6 MB
  unsigned short* WbT = (unsigned short*)(ws + off); off += (size_t)INDIM * CC * 2;  // 128 KB
  float* el = (float*)(ws + off); off += (size_t)NN * HH * 4;   // 1.6 MB
  float* er = (float*)(ws + off); off += (size_t)NN * HH * 4;   // 1.6 MB
  int* counts8 = (int*)(ws + off); off += (size_t)NREP * NN * 4; // 1.6 MB (memset)
  int* row_start = (int*)(ws + off); off += (size_t)NN * 4;
  int* partial   = (int*)(ws + off); off += 256;
  unsigned char* offs8 = (unsigned char*)(ws + off); off += (size_t)NN * 8;   // 400 KB
  unsigned short* s16    = (unsigned short*)(ws + off); off += (size_t)EE * 2; // 1.6 MB
  unsigned short* d16    = (unsigned short*)(ws + off); off += (size_t)EE * 2; // 1.6 MB
  unsigned short* slot16 = (unsigned short*)(ws + off); off += (size_t)EE * 2; // 1.6 MB
  unsigned short* csr16  = (unsigned short*)(ws + off); off += (size_t)EE * 2; // 1.6 MB

  hipMemsetAsync(counts8, 0, (size_t)NREP * NN * 4, stream);

  k_prep<<<PREP_GRID, 256, 0, stream>>>((const unsigned*)src_raw, (const unsigned*)dst_raw,
                                        counts8, s16, d16, slot16, W, WbT);

  k_gemm<<<(NN + 63) / 64, 512, 0, stream>>>(h, WbT, attn_w, z, el, er);

  k_scan<<<NSCAN, 1024, 0, stream>>>(counts8, row_start, partial, offs8);

  k_scatter<<<2048, 256, 0, stream>>>(s16, d16, slot16, offs8, row_start, partial, csr16);

  k_agg<<<AGG_WAVES / 4, 256, 0, stream>>>(z, el, er, row_start, partial, csr16, out);
}

// Round 12
// 146.592 us; speedup vs baseline: 1.3180x; 1.1331x over previous
//
#include <hip/hip_runtime.h>
#include <math.h>

#define NN 50000
#define EE 800000
#define INDIM 256
#define DD 32
#define HH 8
#define CC 256   // H*D
#define NEG 0.01f
#define NREP 8        // counter replicas == XCD count (rep-major => XCD-local lines)
#define NSCAN 49      // ceil(NN/1024)
#define PREP_GRID 1024
#define PREP_STRIDE (PREP_GRID * 256)

typedef __attribute__((ext_vector_type(8))) short bf16x8;
typedef __attribute__((ext_vector_type(4))) float f32x4;

__device__ __forceinline__ unsigned short f32_to_bf16_rne(float f) {
  unsigned u = __float_as_uint(f);
  u += 0x7fffu + ((u >> 16) & 1u);
  return (unsigned short)(u >> 16);
}

// ---------- prep: detect + convert(->ushort) + XCD-local histogram + W->bf16 ----------
__global__ __launch_bounds__(256) void k_prep(const unsigned* __restrict__ sraw,
                                              const unsigned* __restrict__ draw,
                                              int* __restrict__ counts8,
                                              unsigned short* __restrict__ s16,
                                              unsigned short* __restrict__ d16,
                                              unsigned short* __restrict__ slot16,
                                              const float* __restrict__ W,
                                              unsigned short* __restrict__ WbT) {
  __shared__ int sflag;
  if (threadIdx.x == 0) sflag = 0;
  __syncthreads();
  const int gt = blockIdx.x * 256 + threadIdx.x;
  unsigned v = 0;
#pragma unroll
  for (int i = 0; i < 4; ++i) {
    int e = (gt * 4 + i) % (EE / 2);
    v |= sraw[2 * e + 1] | draw[2 * e + 1];
  }
  if (v) atomicOr(&sflag, 1);
  __syncthreads();
  const int is32 = sflag;   // 1 => int32 indices

  const int rep = blockIdx.x & (NREP - 1);
  int* __restrict__ mycounts = counts8 + rep * NN;

  for (int e = gt; e < EE; e += PREP_STRIDE) {
    int sv, dv;
    if (is32) {
      sv = ((const int*)sraw)[e];
      dv = ((const int*)draw)[e];
    } else {
      sv = (int)((const long long*)sraw)[e];
      dv = (int)((const long long*)draw)[e];
    }
    s16[e] = (unsigned short)sv;
    d16[e] = (unsigned short)dv;
    slot16[e] = (unsigned short)atomicAdd(&mycounts[dv], 1);
  }

  // W -> WbT[n][k] = W[h][k][d], n=h*32+d (B^T layout)
  if (gt < INDIM * CC) {
    int n = gt >> 8, k = gt & 255;
    int hh = n >> 5, d = n & 31;
    WbT[gt] = f32_to_bf16_rne(W[(size_t)hh * 8192 + k * 32 + d]);
  }
}

// ---------- z = h @ W via bf16 MFMA; epilogue: el/er + per-(node,head) int8 quantized z ----------
// elsc[node] = { el[8 heads] , scale[8 heads] }  (64 B = 1 cache line)
// z8[node][feat]: int8, dequant = q * scale[head]
__global__ __launch_bounds__(512) void k_gemm(const float* __restrict__ h,
                                              const unsigned short* __restrict__ WbT,
                                              const float* __restrict__ attn_w,
                                              signed char* __restrict__ z8,
                                              float* __restrict__ elsc,
                                              float* __restrict__ er) {
  __shared__ short sA[64 * 256];   // 32 KB, [64 nodes][256 k], chunk-swizzled
  const int t = threadIdx.x;
  const int l = t & 63;
  const int w = t >> 6;            // wave index == head
  const int row0 = blockIdx.x * 64;

#pragma unroll
  for (int i = 0; i < 4; ++i) {
    int q = i * 512 + t;
    int row = q >> 5, c = q & 31;
    int grow = row0 + row; if (grow >= NN) grow = NN - 1;
    const float* src = &h[(size_t)grow * 256 + c * 8];
    float4 f0 = *reinterpret_cast<const float4*>(src);
    float4 f1 = *reinterpret_cast<const float4*>(src + 4);
    bf16x8 vv;
    vv[0] = (short)f32_to_bf16_rne(f0.x); vv[1] = (short)f32_to_bf16_rne(f0.y);
    vv[2] = (short)f32_to_bf16_rne(f0.z); vv[3] = (short)f32_to_bf16_rne(f0.w);
    vv[4] = (short)f32_to_bf16_rne(f1.x); vv[5] = (short)f32_to_bf16_rne(f1.y);
    vv[6] = (short)f32_to_bf16_rne(f1.z); vv[7] = (short)f32_to_bf16_rne(f1.w);
    int sc = c ^ (row & 7);
    *reinterpret_cast<bf16x8*>(&sA[row * 256 + sc * 8]) = vv;
  }

  bf16x8 bf[2][8];
  {
    const int n = w * 32 + (l & 15);
    const int kb = (l >> 4) * 8;
#pragma unroll
    for (int c = 0; c < 2; ++c)
#pragma unroll
      for (int kk = 0; kk < 8; ++kk)
        bf[c][kk] = *reinterpret_cast<const bf16x8*>(
            &WbT[(size_t)(n + c * 16) * 256 + kk * 32 + kb]);
  }

  f32x4 acc[4][2];
#pragma unroll
  for (int m = 0; m < 4; ++m)
#pragma unroll
    for (int c = 0; c < 2; ++c) acc[m][c] = (f32x4){0.f, 0.f, 0.f, 0.f};

  __syncthreads();

#pragma unroll
  for (int kk = 0; kk < 8; ++kk) {
    bf16x8 af[4];
#pragma unroll
    for (int m = 0; m < 4; ++m) {
      int row = m * 16 + (l & 15);
      int chunk = kk * 4 + (l >> 4);
      int sc = chunk ^ (row & 7);
      af[m] = *reinterpret_cast<const bf16x8*>(&sA[row * 256 + sc * 8]);
    }
#pragma unroll
    for (int m = 0; m < 4; ++m)
#pragma unroll
      for (int c = 0; c < 2; ++c)
        acc[m][c] = __builtin_amdgcn_mfma_f32_16x16x32_bf16(bf[c][kk], af[m], acc[m][c], 0, 0, 0);
  }

  // attention coefficients for this lane's 8 feats
  float alc[2][4], arc[2][4];
#pragma unroll
  for (int c = 0; c < 2; ++c)
#pragma unroll
    for (int r = 0; r < 4; ++r) {
      int d = c * 16 + ((l >> 4) << 2) + r;
      alc[c][r] = attn_w[w * 64 + d];
      arc[c][r] = attn_w[w * 64 + 32 + d];
    }

  // epilogue per m: node = row0+m*16+(l&15); 4-lane group {l, l^16, l^32, l^48}
#pragma unroll
  for (int m = 0; m < 4; ++m) {
    int node = row0 + m * 16 + (l & 15);
    float pl = 0.f, pr = 0.f, pm = 0.f;
#pragma unroll
    for (int c = 0; c < 2; ++c)
#pragma unroll
      for (int r = 0; r < 4; ++r) {
        float a = acc[m][c][r];
        pl += a * alc[c][r];
        pr += a * arc[c][r];
        pm = fmaxf(pm, fabsf(a));
      }
    pl += __shfl_xor(pl, 16); pl += __shfl_xor(pl, 32);
    pr += __shfl_xor(pr, 16); pr += __shfl_xor(pr, 32);
    pm = fmaxf(pm, __shfl_xor(pm, 16)); pm = fmaxf(pm, __shfl_xor(pm, 32));
    const float rcp = (pm > 0.f) ? (127.f / pm) : 0.f;

    if (node < NN) {
#pragma unroll
      for (int c = 0; c < 2; ++c) {
        unsigned wq = 0;
#pragma unroll
        for (int r = 0; r < 4; ++r) {
          int q = __float2int_rn(acc[m][c][r] * rcp);
          wq |= ((unsigned)(q & 255)) << (8 * r);
        }
        *reinterpret_cast<unsigned*>(
            &z8[(size_t)node * CC + w * 32 + c * 16 + ((l >> 4) << 2)]) = wq;
      }
      if ((l >> 4) == 0) {
        elsc[(size_t)node * 16 + w] = pl;
        elsc[(size_t)node * 16 + 8 + w] = pm * (1.f / 127.f);
        er[(size_t)node * HH + w] = pr;
      }
    }
  }
}

// ---------- scan: fold 8 rep-counts -> degree scan + per-(node,rep) offsets ----------
__global__ __launch_bounds__(1024) void k_scan(const int* __restrict__ counts8,
                                               int* __restrict__ row_start,
                                               int* __restrict__ partial,
                                               unsigned char* __restrict__ offs8) {
  __shared__ int s[1024];
  const int tid = threadIdx.x;
  const int i = blockIdx.x * 1024 + tid;
  int deg = 0;
  if (i < NN) {
    unsigned pack0 = 0, pack1 = 0;
    int run = 0;
#pragma unroll
    for (int r = 0; r < NREP; ++r) {
      int c = counts8[r * NN + i];
      if (r < 4) pack0 |= (unsigned)run << (8 * r);
      else       pack1 |= (unsigned)run << (8 * (r - 4));
      run += c;
    }
    deg = run;
    uint2 pk; pk.x = pack0; pk.y = pack1;
    *reinterpret_cast<uint2*>(&offs8[(size_t)i * 8]) = pk;
  }
  s[tid] = deg;
  __syncthreads();
  for (int off = 1; off < 1024; off <<= 1) {
    int tv = (tid >= off) ? s[tid - off] : 0;
    __syncthreads();
    s[tid] += tv;
    __syncthreads();
  }
  if (i < NN) row_start[i] = s[tid] - deg;         // exclusive within chunk
  if (tid == 1023) partial[blockIdx.x] = s[1023];  // raw chunk total
}

__device__ __forceinline__ void block_base_scan(const int* __restrict__ partial,
                                                int* __restrict__ sbase) {
  if (threadIdx.x < 64) {
    int l = threadIdx.x;
    int x = (l < NSCAN) ? partial[l] : 0;
    int orig = x;
#pragma unroll
    for (int off = 1; off < 64; off <<= 1) {
      int y = __shfl_up(x, off);
      if (l >= off) x += y;
    }
    sbase[l] = x - orig;
  }
  __syncthreads();
}

// ---------- scatter: atomic-free, contiguous per-node CSR ----------
__global__ __launch_bounds__(256) void k_scatter(const unsigned short* __restrict__ s16,
                                                 const unsigned short* __restrict__ d16,
                                                 const unsigned short* __restrict__ slot16,
                                                 const unsigned char* __restrict__ offs8,
                                                 const int* __restrict__ row_start,
                                                 const int* __restrict__ partial,
                                                 unsigned short* __restrict__ csr16) {
  __shared__ int sbase[64];
  block_base_scan(partial, sbase);
  int stride = gridDim.x * blockDim.x;
  for (int e = blockIdx.x * blockDim.x + threadIdx.x; e < EE; e += stride) {
    int dn = (int)d16[e];
    int rep = ((e & (PREP_STRIDE - 1)) >> 8) & (NREP - 1);
    int pos = row_start[dn] + sbase[dn >> 10] + (int)offs8[dn * 8 + rep] + (int)slot16[e];
    csr16[pos] = s16[e];
  }
}

// ---------- per-node softmax-aggregate: int8 z + packed el/scale ----------
#define AGG_WAVES 8192
__global__ __launch_bounds__(256) void k_agg(const signed char* __restrict__ z8,
                                             const float* __restrict__ elsc,
                                             const float* __restrict__ er,
                                             const int* __restrict__ row_start,
                                             const int* __restrict__ partial,
                                             const unsigned short* __restrict__ csr16,
                                             float* __restrict__ out) {
  __shared__ int sbase[64];
  block_base_scan(partial, sbase);

  const int gw = blockIdx.x * 4 + (threadIdx.x >> 6);
  const int l = threadIdx.x & 63;
  const int head = l >> 3;

  for (int n = gw; n < NN; n += AGG_WAVES) {
    const int beg = row_start[n] + sbase[n >> 10];
    const int end = (n == NN - 1) ? EE : (row_start[n + 1] + sbase[(n + 1) >> 10]);
    const float ern = er[(size_t)n * HH + head];

    float den = 0.f;
    float a0 = 0.f, a1 = 0.f, a2 = 0.f, a3 = 0.f;
#pragma unroll 4
    for (int p = beg; p < end; ++p) {
      int s = (int)csr16[p];
      float v = elsc[(size_t)s * 16 + head] + ern;
      v = (v > 0.f) ? v : v * NEG;
      float wgt = __expf(v);
      float sc = elsc[(size_t)s * 16 + 8 + head];
      unsigned wq = *reinterpret_cast<const unsigned*>(&z8[(size_t)s * CC + 4 * l]);
      den += wgt;
      float ws = wgt * sc;
      a0 += ws * (float)(int)(signed char)(wq & 255);
      a1 += ws * (float)(int)(signed char)((wq >> 8) & 255);
      a2 += ws * (float)(int)(signed char)((wq >> 16) & 255);
      a3 += ws * (float)(int)(signed char)(wq >> 24);
    }
    const float rd = (end > beg) ? (1.f / den) : 0.f;
    float4 o;
    o.x = a0 * rd; o.y = a1 * rd; o.z = a2 * rd; o.w = a3 * rd;
    *reinterpret_cast<float4*>(&out[(size_t)n * CC + 4 * l]) = o;
  }
}

extern "C" void kernel_launch(void* const* d_in, const int* in_sizes, int n_in,
                              void* d_out, int out_size, void* d_ws, size_t ws_size,
                              hipStream_t stream) {
  const float* h      = (const float*)d_in[0];
  const float* W      = (const float*)d_in[1];
  const float* attn_w = (const float*)d_in[2];
  const void*  src_raw = d_in[3];
  const void*  dst_raw = d_in[4];
  float* out = (float*)d_out;

  char* ws = (char*)d_ws;
  size_t off = 0;
  signed char* z8     = (signed char*)(ws + off); off += (size_t)NN * CC;            // 12.8 MB
  unsigned short* WbT = (unsigned short*)(ws + off); off += (size_t)INDIM * CC * 2;  // 128 KB
  float* elsc = (float*)(ws + off); off += (size_t)NN * 16 * 4;  // 3.2 MB (el[8]+scale[8])
  float* er   = (float*)(ws + off); off += (size_t)NN * HH * 4;  // 1.6 MB
  int* counts8 = (int*)(ws + off); off += (size_t)NREP * NN * 4; // 1.6 MB (memset)
  int* row_start = (int*)(ws + off); off += (size_t)NN * 4;
  int* partial   = (int*)(ws + off); off += 256;
  unsigned char* offs8 = (unsigned char*)(ws + off); off += (size_t)NN * 8;   // 400 KB
  unsigned short* s16    = (unsigned short*)(ws + off); off += (size_t)EE * 2; // 1.6 MB
  unsigned short* d16    = (unsigned short*)(ws + off); off += (size_t)EE * 2; // 1.6 MB
  unsigned short* slot16 = (unsigned short*)(ws + off); off += (size_t)EE * 2; // 1.6 MB
  unsigned short* csr16  = (unsigned short*)(ws + off); off += (size_t)EE * 2; // 1.6 MB

  hipMemsetAsync(counts8, 0, (size_t)NREP * NN * 4, stream);

  k_prep<<<PREP_GRID, 256, 0, stream>>>((const unsigned*)src_raw, (const unsigned*)dst_raw,
                                        counts8, s16, d16, slot16, W, WbT);

  k_gemm<<<(NN + 63) / 64, 512, 0, stream>>>(h, WbT, attn_w, z8, elsc, er);

  k_scan<<<NSCAN, 1024, 0, stream>>>(counts8, row_start, partial, offs8);

  k_scatter<<<2048, 256, 0, stream>>>(s16, d16, slot16, offs8, row_start, partial, csr16);

  k_agg<<<AGG_WAVES / 4, 256, 0, stream>>>(z8, elsc, er, row_start, partial, csr16, out);
}